// Round 5
// baseline (251.651 us; speedup 1.0000x reference)
//
#include <hip/hip_runtime.h>

// TGCN graph convolution, float32 in/out.
// B=4, N=1024, input_dim=1, gru=64 -> D=65, H=8 heads, F=8, out=(B,N,128).
//
// Sparse: adj_mask ~3% dense; masked softmax entries are EXACTLY 0 in fp32
// (exp(-1e9-max) underflows), laplacian shares adj's pattern (diag incl).
// Both NxN contractions run over ~31 neighbors/row.
// Laplacian branch reassociated: (lap @ h) @ weights == lap @ (h @ weights).
//
// Round 5: cooperative launch failed under graph capture (round 4: output
// never written). Same fusion via a SOFTWARE grid barrier instead:
//  - grid = 1024 blocks x 256 thr, __launch_bounds__(256,6) caps VGPR <= ~85
//    -> capacity >= 6 blocks/CU = 1536 co-resident >> 1024: no deadlock.
//  - barrier counter in d_ws, zeroed each call by a hipMemsetAsync graph node
//    (memset nodes are graph-capture-legal; the harness itself uses them).
//  - device-scope atomics + __threadfence() for cross-XCD visibility.
// Work remap: block b waves 0-3 do proj rows 4b..4b+3; wave 0 also builds
// CSR row b. Phase 2 identical to the verified round-3 attn kernel.

#define NN 1024
#define BB 4
#define CAP 128    // max neighbors/row (3% -> mean ~31, max ~55)
#define NBLK 1024

__global__ __launch_bounds__(256, 6) void fused_all(
    const float* __restrict__ adj,
    const float* __restrict__ lap,
    const float* __restrict__ inp,
    const float* __restrict__ hid,
    const float* __restrict__ W,
    const float* __restrict__ W2,
    const float* __restrict__ attnv,
    const float* __restrict__ biases,
    int* __restrict__ cnt,
    int* __restrict__ idx,
    float* __restrict__ lapv,
    float* __restrict__ pay,
    float* __restrict__ es,
    float* __restrict__ ed,
    unsigned int* __restrict__ bar,
    float* __restrict__ out)
{
    const int wid  = threadIdx.x >> 6;
    const int lane = threadIdx.x & 63;
    const int blk  = blockIdx.x;

    // ---------------- phase 1a: projections (one wave per (b,n) row) -------
    {
        const int row = blk * 4 + wid;                // [0, 4096)
        const float hv_own = hid[row * 64 + lane];
        const float h0     = inp[row];                // input_dim == 1

        float a1 = h0 * W[lane];
        float a2 = h0 * W2[lane];
        #pragma unroll
        for (int d = 1; d < 65; ++d) {
            const float hv = __shfl(hv_own, d - 1);
            a1 = fmaf(hv, W[d * 64 + lane], a1);
            a2 = fmaf(hv, W2[d * 64 + lane], a2);
        }
        // interleaved payload: [ht_c, hw_c] pairs -> one float2 gather later
        *(float2*)(pay + row * 128 + 2 * lane) = make_float2(a1, a2);

        const int f = lane & 7;
        float ts = a1 * attnv[f];
        float td = a1 * attnv[8 + f];
        #pragma unroll
        for (int w = 1; w <= 4; w <<= 1) {
            ts += __shfl_xor(ts, w);
            td += __shfl_xor(td, w);
        }
        if (f == 0) {
            es[row * 8 + (lane >> 3)] = ts;
            ed[row * 8 + (lane >> 3)] = td;
        }
    }

    // ---------------- phase 1b: CSR build (wave 0, row i = blk) ------------
    if (wid == 0) {
        const int i = blk;
        const float4* arow = (const float4*)(adj + i * NN);
        const float*  lrow = lap + i * NN;
        const unsigned long long lt = (1ull << lane) - 1ull;
        int base = 0;
        #pragma unroll
        for (int it = 0; it < 4; ++it) {
            const float4 a = arow[it * 64 + lane];
            const bool m0 = a.x != 0.0f, m1 = a.y != 0.0f,
                       m2 = a.z != 0.0f, m3 = a.w != 0.0f;
            const unsigned long long b0 = __ballot(m0), b1 = __ballot(m1),
                                     b2 = __ballot(m2), b3 = __ballot(m3);
            int pos = base + __popcll(b0 & lt) + __popcll(b1 & lt)
                           + __popcll(b2 & lt) + __popcll(b3 & lt);
            const int j0 = it * 256 + lane * 4;
            if (m0) { idx[i*CAP+pos] = j0;   lapv[i*CAP+pos] = lrow[j0];   ++pos; }
            if (m1) { idx[i*CAP+pos] = j0+1; lapv[i*CAP+pos] = lrow[j0+1]; ++pos; }
            if (m2) { idx[i*CAP+pos] = j0+2; lapv[i*CAP+pos] = lrow[j0+2]; ++pos; }
            if (m3) { idx[i*CAP+pos] = j0+3; lapv[i*CAP+pos] = lrow[j0+3]; }
            base += __popcll(b0) + __popcll(b1) + __popcll(b2) + __popcll(b3);
        }
        const int c    = base;             // realistic max ~55 << CAP
        const int cpad = (c + 7) & ~7;
        const int pos  = c + lane;         // pad with self-loops, lapv = 0
        if (pos < cpad) { idx[i*CAP+pos] = i; lapv[i*CAP+pos] = 0.0f; }
        if (lane == 0) cnt[i] = c;
    }

    // ---------------- software grid barrier --------------------------------
    __threadfence();            // flush this thread's stores device-wide
    __syncthreads();            // whole block's phase-1 done
    if (threadIdx.x == 0) {
        atomicAdd(bar, 1u);     // device-scope by default
        while (atomicAdd(bar, 0u) < NBLK) {
            __builtin_amdgcn_s_sleep(2);
        }
    }
    __syncthreads();
    __threadfence();            // invalidate caches before reading others' data

    // ---------------- phase 2: attn + laplacian (one wave per (b,i)) -------
    {
        const int row  = blk * 4 + wid;             // (b,i) in [0, 4096)
        const int b    = row >> 10;
        const int i    = row & (NN - 1);
        const int hc   = lane >> 3;                 // consumer head
        const int hp   = lane & 7;                  // producer head
        const int ksub = lane >> 3;                 // producer neighbor sub-idx

        const float es_p = es[row * 8 + hp];
        const int   c    = cnt[i];
        const int   cpad = (c + 7) & ~7;

        float num = 0.0f, lacc = 0.0f, den_p = 0.0f;

        for (int k0 = 0; k0 < cpad; k0 += 8) {
            const int   k   = k0 + ksub;
            const int   jp  = idx[i * CAP + k];     // padded region is valid
            const float lvp = lapv[i * CAP + k];
            const int   jrp = (b << 10) | jp;
            float s = es_p + ed[jrp * 8 + hp];
            s = (s > 0.0f) ? s : 0.2f * s;          // leaky_relu(0.2)
            const float pp = (k < c) ? __expf(s) : 0.0f;
            den_p += pp;

            #pragma unroll
            for (int t = 0; t < 8; ++t) {
                const int   j_t  = __shfl(jp,  t * 8);        // ksub=t
                const float p_t  = __shfl(pp,  t * 8 + hc);   // (ksub=t, h=hc)
                const float lv_t = __shfl(lvp, t * 8);
                const int   jr   = (b << 10) | j_t;
                const float2 v = *(const float2*)(pay + jr * 128 + 2 * lane);
                num  = fmaf(p_t,  v.x, num);
                lacc = fmaf(lv_t, v.y, lacc);
            }
        }

        // den: sum producer partials over lanes sharing hp (stride-8 groups)
        den_p += __shfl_xor(den_p, 8);
        den_p += __shfl_xor(den_p, 16);
        den_p += __shfl_xor(den_p, 32);
        const float den = __shfl(den_p, hc);        // lane hc = head hc's sum

        out[row * 128 + lane]      = num / den;
        out[row * 128 + 64 + lane] = lacc + biases[lane];
    }
}

// ---------------------------------------------------------------------------
extern "C" void kernel_launch(void* const* d_in, const int* in_sizes, int n_in,
                              void* d_out, int out_size, void* d_ws, size_t ws_size,
                              hipStream_t stream) {
    const float* inp    = (const float*)d_in[0];  // (4,1024,1)
    const float* hid    = (const float*)d_in[1];  // (4,1024,64)
    const float* W      = (const float*)d_in[2];  // (65,64)
    const float* attnv  = (const float*)d_in[3];  // (16,1)
    const float* W2     = (const float*)d_in[4];  // (65,64) "weights"
    const float* biases = (const float*)d_in[5];  // (64,)
    const float* adj    = (const float*)d_in[6];  // (1024,1024)
    const float* lap    = (const float*)d_in[7];  // (1024,1024)
    float* out = (float*)d_out;

    float* ws   = (float*)d_ws;
    float* pay  = ws;                        // B*N*128 fp32 (ht|hw interleaved)
    float* es   = pay + BB * NN * 128;       // B*N*8
    float* ed   = es + BB * NN * 8;          // B*N*8
    int*   cnt  = (int*)(ed + BB * NN * 8);  // N
    int*   idx  = cnt + NN;                  // N*CAP
    float* lapv = (float*)(idx + NN * CAP);  // N*CAP
    unsigned int* bar = (unsigned int*)(lapv + NN * CAP);  // 1 counter
    // total ~3.3 MB of d_ws

    hipMemsetAsync(bar, 0, sizeof(unsigned int), stream);  // graph memset node

    fused_all<<<NBLK, 256, 0, stream>>>(
        adj, lap, inp, hid, W, W2, attnv, biases,
        cnt, idx, lapv, pay, es, ed, bar, out);
}

// Round 6
// 183.384 us; speedup vs baseline: 1.3723x; 1.3723x over previous
//
#include <hip/hip_runtime.h>

// TGCN graph convolution, float32 in/out.
// B=4, N=1024, input_dim=1, gru=64 -> D=65, H=8 heads, F=8, out=(B,N,128).
//
// Sparse: adj_mask ~3% dense; masked softmax entries are EXACTLY 0 in fp32
// (exp(-1e9-max) underflows), laplacian shares adj's pattern (diag incl).
// Both NxN contractions run over ~31 neighbors/row.
// Laplacian branch reassociated: (lap @ h) @ weights == lap @ (h @ weights).
//
// Round 6: round-5's software grid barrier was correct but spun with
// same-address atomicAdd RMWs from 1024 waves -> ~265us of coherence-point
// serialization (VALUBusy 1.4%). Fix:
//  - spin = __hip_atomic_load (RELAXED, AGENT) — coherent LOAD, no RMW queue;
//  - arrival = 16-way tree: group counters 128B apart, fire-and-forget
//    relaxed adds (64 per line, parallel across 16 lines), last-in-group
//    bumps root; release when root == 16;
//  - same __threadfence() placement as round 5 (proven correct for
//    cross-XCD visibility), s_sleep(4) backoff.
// Grid 1024 blocks x 256 thr, __launch_bounds__(256,6): capacity 1536 >=
// 1024 co-resident -> no deadlock. Counters zeroed per call by a
// hipMemsetAsync graph node.

#define NN 1024
#define BB 4
#define CAP 128    // max neighbors/row (3% -> mean ~31, max ~55)
#define NBLK 1024
#define NGRP 16    // arrival-tree fan-in

__global__ __launch_bounds__(256, 6) void fused_all(
    const float* __restrict__ adj,
    const float* __restrict__ lap,
    const float* __restrict__ inp,
    const float* __restrict__ hid,
    const float* __restrict__ W,
    const float* __restrict__ W2,
    const float* __restrict__ attnv,
    const float* __restrict__ biases,
    int* __restrict__ cnt,
    int* __restrict__ idx,
    float* __restrict__ lapv,
    float* __restrict__ pay,
    float* __restrict__ es,
    float* __restrict__ ed,
    unsigned int* __restrict__ bar,   // [0]=root, [32 + g*32]=group g
    float* __restrict__ out)
{
    const int wid  = threadIdx.x >> 6;
    const int lane = threadIdx.x & 63;
    const int blk  = blockIdx.x;

    // ---------------- phase 1a: projections (one wave per (b,n) row) -------
    {
        const int row = blk * 4 + wid;                // [0, 4096)
        const float hv_own = hid[row * 64 + lane];
        const float h0     = inp[row];                // input_dim == 1

        float a1 = h0 * W[lane];
        float a2 = h0 * W2[lane];
        #pragma unroll
        for (int d = 1; d < 65; ++d) {
            const float hv = __shfl(hv_own, d - 1);
            a1 = fmaf(hv, W[d * 64 + lane], a1);
            a2 = fmaf(hv, W2[d * 64 + lane], a2);
        }
        // interleaved payload: [ht_c, hw_c] pairs -> one float2 gather later
        *(float2*)(pay + row * 128 + 2 * lane) = make_float2(a1, a2);

        const int f = lane & 7;
        float ts = a1 * attnv[f];
        float td = a1 * attnv[8 + f];
        #pragma unroll
        for (int w = 1; w <= 4; w <<= 1) {
            ts += __shfl_xor(ts, w);
            td += __shfl_xor(td, w);
        }
        if (f == 0) {
            es[row * 8 + (lane >> 3)] = ts;
            ed[row * 8 + (lane >> 3)] = td;
        }
    }

    // ---------------- phase 1b: CSR build (wave 0, row i = blk) ------------
    if (wid == 0) {
        const int i = blk;
        const float4* arow = (const float4*)(adj + i * NN);
        const float*  lrow = lap + i * NN;
        const unsigned long long lt = (1ull << lane) - 1ull;
        int base = 0;
        #pragma unroll
        for (int it = 0; it < 4; ++it) {
            const float4 a = arow[it * 64 + lane];
            const bool m0 = a.x != 0.0f, m1 = a.y != 0.0f,
                       m2 = a.z != 0.0f, m3 = a.w != 0.0f;
            const unsigned long long b0 = __ballot(m0), b1 = __ballot(m1),
                                     b2 = __ballot(m2), b3 = __ballot(m3);
            int pos = base + __popcll(b0 & lt) + __popcll(b1 & lt)
                           + __popcll(b2 & lt) + __popcll(b3 & lt);
            const int j0 = it * 256 + lane * 4;
            if (m0) { idx[i*CAP+pos] = j0;   lapv[i*CAP+pos] = lrow[j0];   ++pos; }
            if (m1) { idx[i*CAP+pos] = j0+1; lapv[i*CAP+pos] = lrow[j0+1]; ++pos; }
            if (m2) { idx[i*CAP+pos] = j0+2; lapv[i*CAP+pos] = lrow[j0+2]; ++pos; }
            if (m3) { idx[i*CAP+pos] = j0+3; lapv[i*CAP+pos] = lrow[j0+3]; }
            base += __popcll(b0) + __popcll(b1) + __popcll(b2) + __popcll(b3);
        }
        const int c    = base;             // realistic max ~55 << CAP
        const int cpad = (c + 7) & ~7;
        const int pos  = c + lane;         // pad with self-loops, lapv = 0
        if (pos < cpad) { idx[i*CAP+pos] = i; lapv[i*CAP+pos] = 0.0f; }
        if (lane == 0) cnt[i] = c;
    }

    // ---------------- software grid barrier (load-spin, tree arrival) ------
    __threadfence();            // make phase-1 stores device-visible
    __syncthreads();            // whole block's phase-1 done
    if (threadIdx.x == 0) {
        unsigned int* grp = bar + 32 + (blk & (NGRP - 1)) * 32;  // 128B apart
        const unsigned int prev =
            __hip_atomic_fetch_add(grp, 1u, __ATOMIC_RELAXED,
                                   __HIP_MEMORY_SCOPE_AGENT);
        if (prev == (NBLK / NGRP - 1)) {
            __hip_atomic_fetch_add(bar, 1u, __ATOMIC_RELAXED,
                                   __HIP_MEMORY_SCOPE_AGENT);
        }
        while (__hip_atomic_load(bar, __ATOMIC_RELAXED,
                                 __HIP_MEMORY_SCOPE_AGENT) < NGRP) {
            __builtin_amdgcn_s_sleep(4);
        }
    }
    __syncthreads();
    __threadfence();            // acquire: drop stale cached lines

    // ---------------- phase 2: attn + laplacian (one wave per (b,i)) -------
    {
        const int row  = blk * 4 + wid;             // (b,i) in [0, 4096)
        const int b    = row >> 10;
        const int i    = row & (NN - 1);
        const int hc   = lane >> 3;                 // consumer head
        const int hp   = lane & 7;                  // producer head
        const int ksub = lane >> 3;                 // producer neighbor sub-idx

        const float es_p = es[row * 8 + hp];
        const int   c    = cnt[i];
        const int   cpad = (c + 7) & ~7;

        float num = 0.0f, lacc = 0.0f, den_p = 0.0f;

        for (int k0 = 0; k0 < cpad; k0 += 8) {
            const int   k   = k0 + ksub;
            const int   jp  = idx[i * CAP + k];     // padded region is valid
            const float lvp = lapv[i * CAP + k];
            const int   jrp = (b << 10) | jp;
            float s = es_p + ed[jrp * 8 + hp];
            s = (s > 0.0f) ? s : 0.2f * s;          // leaky_relu(0.2)
            const float pp = (k < c) ? __expf(s) : 0.0f;
            den_p += pp;

            #pragma unroll
            for (int t = 0; t < 8; ++t) {
                const int   j_t  = __shfl(jp,  t * 8);        // ksub=t
                const float p_t  = __shfl(pp,  t * 8 + hc);   // (ksub=t, h=hc)
                const float lv_t = __shfl(lvp, t * 8);
                const int   jr   = (b << 10) | j_t;
                const float2 v = *(const float2*)(pay + jr * 128 + 2 * lane);
                num  = fmaf(p_t,  v.x, num);
                lacc = fmaf(lv_t, v.y, lacc);
            }
        }

        // den: sum producer partials over lanes sharing hp (stride-8 groups)
        den_p += __shfl_xor(den_p, 8);
        den_p += __shfl_xor(den_p, 16);
        den_p += __shfl_xor(den_p, 32);
        const float den = __shfl(den_p, hc);        // lane hc = head hc's sum

        out[row * 128 + lane]      = num / den;
        out[row * 128 + 64 + lane] = lacc + biases[lane];
    }
}

// ---------------------------------------------------------------------------
extern "C" void kernel_launch(void* const* d_in, const int* in_sizes, int n_in,
                              void* d_out, int out_size, void* d_ws, size_t ws_size,
                              hipStream_t stream) {
    const float* inp    = (const float*)d_in[0];  // (4,1024,1)
    const float* hid    = (const float*)d_in[1];  // (4,1024,64)
    const float* W      = (const float*)d_in[2];  // (65,64)
    const float* attnv  = (const float*)d_in[3];  // (16,1)
    const float* W2     = (const float*)d_in[4];  // (65,64) "weights"
    const float* biases = (const float*)d_in[5];  // (64,)
    const float* adj    = (const float*)d_in[6];  // (1024,1024)
    const float* lap    = (const float*)d_in[7];  // (1024,1024)
    float* out = (float*)d_out;

    float* ws   = (float*)d_ws;
    float* pay  = ws;                        // B*N*128 fp32 (ht|hw interleaved)
    float* es   = pay + BB * NN * 128;       // B*N*8
    float* ed   = es + BB * NN * 8;          // B*N*8
    int*   cnt  = (int*)(ed + BB * NN * 8);  // N
    int*   idx  = cnt + NN;                  // N*CAP
    float* lapv = (float*)(idx + NN * CAP);  // N*CAP
    unsigned int* bar = (unsigned int*)(lapv + NN * CAP);  // root + 16 groups
    // total ~3.3 MB of d_ws

    // zero root + group counters (root at [0], groups at [32 + g*32])
    hipMemsetAsync(bar, 0, (32 + NGRP * 32) * sizeof(unsigned int), stream);

    fused_all<<<NBLK, 256, 0, stream>>>(
        adj, lap, inp, hid, W, W2, attnv, biases,
        cnt, idx, lapv, pay, es, ed, bar, out);
}

// Round 7
// 29.911 us; speedup vs baseline: 8.4132x; 6.1309x over previous
//
#include <hip/hip_runtime.h>

// TGCN graph convolution, float32 in/out.
// B=4, N=1024, input_dim=1, gru=64 -> D=65, H=8 heads, F=8, out=(B,N,128).
//
// Sparse: adj_mask ~3% dense; masked softmax entries are EXACTLY 0 in fp32,
// laplacian shares adj's pattern. Both NxN contractions -> ~31 neighbors/row.
// Laplacian branch reassociated: (lap @ h) @ weights == lap @ (h @ weights).
//
// Round 7: rounds 5/6 showed the software grid barrier's two killers:
// (a) 1024 spinners on ONE cache line serialize at the coherence point;
// (b) __threadfence() = full per-XCD L2 writeback/invalidate, x1024 blocks.
// Fix:
//  - NO threadfence. Only truly-shared arrays (pay, ed) cross blocks; they
//    are accessed with relaxed AGENT-scope atomics (sc1: bypass the
//    non-coherent per-XCD L2, hit the device coherence point directly).
//    s_waitcnt vmcnt(0) before arrival ensures stores completed.
//  - CSR lists now BLOCK-LOCAL (each wave builds the row it consumes, into
//    LDS; 4x redundant build is ~nothing). es stays in registers via shfl.
//  - Barrier spread across lines: 3-level arrival tree (128 leaves x8,
//    16 supers x8, root x16) + 128 release words (8 spinners/line,
//    s_sleep(32)). No line sees >16 RMWs or high-rate polling.
// Grid 1024 x 256, __launch_bounds__(256,6): capacity 1536 >= 1024
// co-resident -> no deadlock. Counters zeroed per call via hipMemsetAsync.

#define NN 1024
#define BB 4
#define NBLK 1024
#define LCAP 96    // per-row neighbor cap in LDS (deg ~31 mean, ~55 max)

typedef unsigned int u32;
typedef unsigned long long u64;

__device__ __forceinline__ void st_agent_u64(float* p, u64 v) {
    __hip_atomic_store((u64*)p, v, __ATOMIC_RELAXED, __HIP_MEMORY_SCOPE_AGENT);
}
__device__ __forceinline__ void st_agent_u32(float* p, u32 v) {
    __hip_atomic_store((u32*)p, v, __ATOMIC_RELAXED, __HIP_MEMORY_SCOPE_AGENT);
}
__device__ __forceinline__ u64 ld_agent_u64(const float* p) {
    return __hip_atomic_load((const u64*)p, __ATOMIC_RELAXED, __HIP_MEMORY_SCOPE_AGENT);
}
__device__ __forceinline__ u32 ld_agent_u32(const float* p) {
    return __hip_atomic_load((const u32*)p, __ATOMIC_RELAXED, __HIP_MEMORY_SCOPE_AGENT);
}

__global__ __launch_bounds__(256, 6) void fused_all(
    const float* __restrict__ adj,
    const float* __restrict__ lap,
    const float* __restrict__ inp,
    const float* __restrict__ hid,
    const float* __restrict__ W,
    const float* __restrict__ W2,
    const float* __restrict__ attnv,
    const float* __restrict__ biases,
    float* __restrict__ pay,      // B*N*128: [ht|hw] interleaved, AGENT scope
    float* __restrict__ ed,       // B*N*8, AGENT scope
    u32*   __restrict__ bar,      // [0]=root, 32*(1+s)=supers, 32*(17+l)=leaves,
                                  // 32*(145+g)=release words (128B strides)
    float* __restrict__ out)
{
    __shared__ int   idx_s[4][LCAP];
    __shared__ float lapv_s[4][LCAP];
    __shared__ int   cnt_s[4];

    const int wid  = threadIdx.x >> 6;
    const int lane = threadIdx.x & 63;
    const int blk  = blockIdx.x;
    const int row  = blk * 4 + wid;            // (b,i) flat in [0,4096)
    const int b    = row >> 10;
    const int i    = row & (NN - 1);

    // ---------------- phase 1a: projection of own row ----------------------
    const float hv_own = hid[row * 64 + lane];
    const float h0     = inp[row];             // input_dim == 1
    float a1 = h0 * W[lane];
    float a2 = h0 * W2[lane];
    #pragma unroll
    for (int d = 1; d < 65; ++d) {
        const float hv = __shfl(hv_own, d - 1);
        a1 = fmaf(hv, W[d * 64 + lane], a1);
        a2 = fmaf(hv, W2[d * 64 + lane], a2);
    }
    {   // shared across blocks -> agent-scope (L2-bypassing) store
        float2 pv = make_float2(a1, a2);
        u64 pu; __builtin_memcpy(&pu, &pv, 8);
        st_agent_u64(pay + row * 128 + 2 * lane, pu);
    }

    const int f = lane & 7;
    float ts = a1 * attnv[f];                  // es (stays in registers)
    float td = a1 * attnv[8 + f];              // ed (shared -> global)
    #pragma unroll
    for (int w = 1; w <= 4; w <<= 1) {
        ts += __shfl_xor(ts, w);
        td += __shfl_xor(td, w);
    }
    if (f == 0) {
        u32 tu; __builtin_memcpy(&tu, &td, 4);
        st_agent_u32(ed + row * 8 + (lane >> 3), tu);
    }

    // ---------------- phase 1b: CSR of row i into LDS (own wave) -----------
    {
        const float4* arow = (const float4*)(adj + i * NN);
        const float*  lrow = lap + i * NN;
        const u64 lt = (1ull << lane) - 1ull;
        int base = 0;
        #pragma unroll
        for (int it = 0; it < 4; ++it) {
            const float4 a = arow[it * 64 + lane];
            const bool m0 = a.x != 0.0f, m1 = a.y != 0.0f,
                       m2 = a.z != 0.0f, m3 = a.w != 0.0f;
            const u64 b0 = __ballot(m0), b1 = __ballot(m1),
                      b2 = __ballot(m2), b3 = __ballot(m3);
            int pos = base + __popcll(b0 & lt) + __popcll(b1 & lt)
                           + __popcll(b2 & lt) + __popcll(b3 & lt);
            const int j0 = it * 256 + lane * 4;
            if (m0) { idx_s[wid][pos] = j0;   lapv_s[wid][pos] = lrow[j0];   ++pos; }
            if (m1) { idx_s[wid][pos] = j0+1; lapv_s[wid][pos] = lrow[j0+1]; ++pos; }
            if (m2) { idx_s[wid][pos] = j0+2; lapv_s[wid][pos] = lrow[j0+2]; ++pos; }
            if (m3) { idx_s[wid][pos] = j0+3; lapv_s[wid][pos] = lrow[j0+3]; }
            base += __popcll(b0) + __popcll(b1) + __popcll(b2) + __popcll(b3);
        }
        const int c    = base;                 // max ~55 << LCAP
        const int cpad = (c + 7) & ~7;
        if (c + lane < cpad) {                 // pad with self-loops, lapv=0
            idx_s[wid][c + lane] = i; lapv_s[wid][c + lane] = 0.0f;
        }
        if (lane == 0) cnt_s[wid] = c;
    }

    // ---------------- grid barrier (spread lines, no fences) ---------------
    asm volatile("s_waitcnt vmcnt(0)" ::: "memory");  // agent stores done
    __syncthreads();
    if (threadIdx.x == 0) {
        const int leaf = blk & 127;
        u32* leafc = bar + 32 * (17 + leaf);
        u32* relw  = bar + 32 * (145 + leaf);
        const u32 p = __hip_atomic_fetch_add(leafc, 1u, __ATOMIC_RELAXED,
                                             __HIP_MEMORY_SCOPE_AGENT);
        if (p == 7) {                          // 8 blocks per leaf
            u32* supc = bar + 32 * (1 + (leaf >> 3));
            const u32 q = __hip_atomic_fetch_add(supc, 1u, __ATOMIC_RELAXED,
                                                 __HIP_MEMORY_SCOPE_AGENT);
            if (q == 7) {                      // 8 leaves per super
                const u32 r = __hip_atomic_fetch_add(bar, 1u, __ATOMIC_RELAXED,
                                                     __HIP_MEMORY_SCOPE_AGENT);
                if (r == 15) {                 // 16 supers -> release everyone
                    for (int g = 0; g < 128; ++g)
                        __hip_atomic_store(bar + 32 * (145 + g), 1u,
                                           __ATOMIC_RELAXED,
                                           __HIP_MEMORY_SCOPE_AGENT);
                }
            }
        }
        while (__hip_atomic_load(relw, __ATOMIC_RELAXED,
                                 __HIP_MEMORY_SCOPE_AGENT) == 0) {
            __builtin_amdgcn_s_sleep(32);
        }
    }
    __syncthreads();

    // ---------------- phase 2: attn + laplacian (own row) ------------------
    {
        const int hc   = lane >> 3;            // consumer head
        const int hp   = lane & 7;             // producer head
        const int ksub = lane >> 3;            // producer neighbor sub-idx

        const float es_p = __shfl(ts, hp << 3);   // es[hp] from own registers
        const int   c    = cnt_s[wid];
        const int   cpad = (c + 7) & ~7;

        float num = 0.0f, lacc = 0.0f, den_p = 0.0f;

        for (int k0 = 0; k0 < cpad; k0 += 8) {
            const int   k   = k0 + ksub;
            const int   jp  = idx_s[wid][k];   // padded region is valid
            const float lvp = lapv_s[wid][k];
            const int   jrp = (b << 10) | jp;
            const u32 eu = ld_agent_u32(ed + jrp * 8 + hp);
            float edv; __builtin_memcpy(&edv, &eu, 4);
            float s = es_p + edv;
            s = (s > 0.0f) ? s : 0.2f * s;     // leaky_relu(0.2)
            const float pp = (k < c) ? __expf(s) : 0.0f;
            den_p += pp;

            #pragma unroll
            for (int t = 0; t < 8; ++t) {
                const int   j_t  = __shfl(jp,  t * 8);        // ksub=t
                const float p_t  = __shfl(pp,  t * 8 + hc);   // (ksub=t, h=hc)
                const float lv_t = __shfl(lvp, t * 8);
                const int   jr   = (b << 10) | j_t;
                const u64 vu = ld_agent_u64(pay + jr * 128 + 2 * lane);
                float2 v; __builtin_memcpy(&v, &vu, 8);
                num  = fmaf(p_t,  v.x, num);
                lacc = fmaf(lv_t, v.y, lacc);
            }
        }

        // den: sum producer partials over lanes sharing hp (stride-8 groups)
        den_p += __shfl_xor(den_p, 8);
        den_p += __shfl_xor(den_p, 16);
        den_p += __shfl_xor(den_p, 32);
        const float den = __shfl(den_p, hc);   // lane hc = head hc's sum

        out[row * 128 + lane]      = num / den;
        out[row * 128 + 64 + lane] = lacc + biases[lane];
    }
}

// ---------------------------------------------------------------------------
extern "C" void kernel_launch(void* const* d_in, const int* in_sizes, int n_in,
                              void* d_out, int out_size, void* d_ws, size_t ws_size,
                              hipStream_t stream) {
    const float* inp    = (const float*)d_in[0];  // (4,1024,1)
    const float* hid    = (const float*)d_in[1];  // (4,1024,64)
    const float* W      = (const float*)d_in[2];  // (65,64)
    const float* attnv  = (const float*)d_in[3];  // (16,1)
    const float* W2     = (const float*)d_in[4];  // (65,64) "weights"
    const float* biases = (const float*)d_in[5];  // (64,)
    const float* adj    = (const float*)d_in[6];  // (1024,1024)
    const float* lap    = (const float*)d_in[7];  // (1024,1024)
    float* out = (float*)d_out;

    float* ws  = (float*)d_ws;
    float* pay = ws;                          // B*N*128 fp32 (2 MB)
    float* ed  = pay + BB * NN * 128;         // B*N*8 (128 KB)
    u32*   bar = (u32*)(ed + BB * NN * 8);    // 32*(145+128) u32 (~35 KB)

    // zero root + supers + leaves + release words each call (graph-legal)
    hipMemsetAsync(bar, 0, 32 * (145 + 128) * sizeof(u32), stream);

    fused_all<<<NBLK, 256, 0, stream>>>(
        adj, lap, inp, hid, W, W2, attnv, biases, pay, ed, bar, out);
}